// Round 1
// baseline (125.379 us; speedup 1.0000x reference)
//
#include <hip/hip_runtime.h>
#include <hip/hip_bf16.h>

#define M_DIM 32768
#define K_DIM 1024
#define N_POOL 1024

#define BM 128
#define BN 128
#define BK 64

typedef __attribute__((ext_vector_type(8))) short bf16x8;
typedef __attribute__((ext_vector_type(4))) float f32x4;

typedef __attribute__((address_space(3))) unsigned int lds_uint;
typedef const __attribute__((address_space(1))) unsigned int g_uint;

__device__ __forceinline__ unsigned short f2bf(float f) {
    // round-to-nearest-even f32 -> bf16
    unsigned int u = __builtin_bit_cast(unsigned int, f);
    unsigned int lsb = (u >> 16) & 1u;
    u += 0x7fffu + lsb;
    return (unsigned short)(u >> 16);
}

// ---------------- prep: fold avgpool(k=4) into weight/bias, cast to bf16 ----
__global__ __launch_bounds__(256) void prep_kernel(
        const float* __restrict__ W, const float* __restrict__ b,
        unsigned short* __restrict__ wp, float* __restrict__ bp) {
    int n = blockIdx.x;          // 0..1023 pooled output channel
    int t = threadIdx.x;         // 0..255, 4 k's each
    const float4* r0 = (const float4*)(W + (size_t)(4 * n + 0) * K_DIM);
    const float4* r1 = (const float4*)(W + (size_t)(4 * n + 1) * K_DIM);
    const float4* r2 = (const float4*)(W + (size_t)(4 * n + 2) * K_DIM);
    const float4* r3 = (const float4*)(W + (size_t)(4 * n + 3) * K_DIM);
    float4 a0 = r0[t], a1 = r1[t], a2 = r2[t], a3 = r3[t];
    float sx = (a0.x + a1.x + a2.x + a3.x) * 0.25f;
    float sy = (a0.y + a1.y + a2.y + a3.y) * 0.25f;
    float sz = (a0.z + a1.z + a2.z + a3.z) * 0.25f;
    float sw = (a0.w + a1.w + a2.w + a3.w) * 0.25f;
    ushort4 h;
    h.x = f2bf(sx); h.y = f2bf(sy); h.z = f2bf(sz); h.w = f2bf(sw);
    *(ushort4*)&wp[(size_t)n * K_DIM + t * 4] = h;
    if (t == 0)
        bp[n] = 0.25f * (b[4 * n] + b[4 * n + 1] + b[4 * n + 2] + b[4 * n + 3]);
}

// ---------------- GEMM + fused bias/gelu/rowmax partial ---------------------
__global__ __launch_bounds__(256, 2) void gemm_kernel(
        const float* __restrict__ x, const unsigned short* __restrict__ wp,
        const float* __restrict__ bp, float* __restrict__ partial) {
    __shared__ unsigned short As[BM * BK];   // 16 KB, row-major [m][k]
    __shared__ unsigned short Bs[BN * BK];   // 16 KB, row-major [n][k]

    // XCD-chunked swizzle: each XCD owns 32 consecutive m-tiles x all 8 n-tiles
    int bid = blockIdx.x;
    int wg = (bid & 7) * 256 + (bid >> 3);
    int nblk = wg & 7;
    int mblk = wg >> 3;
    int m0 = mblk * BM;
    int n0 = nblk * BN;

    int tid = threadIdx.x;
    int lane = tid & 63;
    int wid = tid >> 6;
    int wr = wid >> 1, wc = wid & 1;   // 2x2 wave grid, each wave 64x64

    f32x4 acc[4][4];
#pragma unroll
    for (int i = 0; i < 4; ++i)
#pragma unroll
        for (int j = 0; j < 4; ++j)
            acc[i][j] = (f32x4)(0.0f);

    const float4* xg = (const float4*)x;

    for (int kt = 0; kt < K_DIM / BK; ++kt) {
        __syncthreads();   // previous tile's LDS reads done
        // ---- B stage: 16 x global_load_lds dwordx4 (bf16 already) ----
#pragma unroll
        for (int i = 0; i < 4; ++i) {
            int ii = wid * 4 + i;
            int n = n0 + ii * 8 + (lane >> 3);
            int kc = kt * BK + (lane & 7) * 8;
            __builtin_amdgcn_global_load_lds(
                (g_uint*)(wp + (size_t)n * K_DIM + kc),
                (lds_uint*)&Bs[ii * 512], 16, 0, 0);
        }
        // ---- A stage: f32 global -> reg -> bf16 -> LDS ----
        float4 av[8];
#pragma unroll
        for (int j = 0; j < 8; ++j) {
            int f = tid + j * 256;                 // float4 index in tile
            int row = f >> 4, c4 = f & 15;
            av[j] = xg[(size_t)(m0 + row) * 256 + kt * 16 + c4];
        }
#pragma unroll
        for (int j = 0; j < 8; ++j) {
            int f = tid + j * 256;
            ushort4 h;
            h.x = f2bf(av[j].x); h.y = f2bf(av[j].y);
            h.z = f2bf(av[j].z); h.w = f2bf(av[j].w);
            *(ushort4*)&As[f * 4] = h;
        }
        __syncthreads();   // drains vmcnt (global_load_lds) + lgkmcnt

        // ---- compute: 2 x (8 ds_read_b128 + 16 MFMA) ----
#pragma unroll
        for (int kk = 0; kk < BK; kk += 32) {
            int aK = kk + (lane >> 4) * 8;
            bf16x8 af[4], bff[4];
#pragma unroll
            for (int mi = 0; mi < 4; ++mi) {
                int r = wr * 64 + mi * 16 + (lane & 15);
                af[mi] = *(const bf16x8*)&As[r * BK + aK];
            }
#pragma unroll
            for (int ni = 0; ni < 4; ++ni) {
                int r = wc * 64 + ni * 16 + (lane & 15);
                bff[ni] = *(const bf16x8*)&Bs[r * BK + aK];
            }
#pragma unroll
            for (int mi = 0; mi < 4; ++mi)
#pragma unroll
                for (int ni = 0; ni < 4; ++ni)
                    acc[mi][ni] = __builtin_amdgcn_mfma_f32_16x16x32_bf16(
                        af[mi], bff[ni], acc[mi][ni], 0, 0, 0);
        }
    }

    // ---- epilogue: bias + tanh-gelu*2 + row-max over this 64-col slice ----
    float bv[4];
#pragma unroll
    for (int ni = 0; ni < 4; ++ni)
        bv[ni] = bp[n0 + wc * 64 + ni * 16 + (lane & 15)];

    const float GC = 0.7978845608028654f;
#pragma unroll
    for (int mi = 0; mi < 4; ++mi) {
#pragma unroll
        for (int j = 0; j < 4; ++j) {
            float mx = -3.4e38f;
#pragma unroll
            for (int ni = 0; ni < 4; ++ni) {
                float y = acc[mi][ni][j] + bv[ni];
                float z = GC * (y + 0.044715f * y * y * y);
                float e = __expf(2.0f * z);
                float th = 1.0f - 2.0f / (e + 1.0f);   // tanh(z)
                float g = y * (1.0f + th);             // 0.5*(1+tanh)*y*SCALE(2)
                mx = fmaxf(mx, g);
            }
#pragma unroll
            for (int s = 1; s < 16; s <<= 1)
                mx = fmaxf(mx, __shfl_xor(mx, s, 64));
            if ((lane & 15) == 0) {
                int grow = m0 + wr * 64 + mi * 16 + (lane >> 4) * 4 + j;
                partial[(size_t)(nblk * 2 + wc) * M_DIM + grow] = mx;
            }
        }
    }
}

// ---------------- final reduce: max over 16 column-chunks -------------------
__global__ __launch_bounds__(256) void reduce_kernel(
        const float* __restrict__ partial, float* __restrict__ out) {
    int m = blockIdx.x * 256 + threadIdx.x;
    float mx = -3.4e38f;
#pragma unroll
    for (int c = 0; c < 16; ++c)
        mx = fmaxf(mx, partial[(size_t)c * M_DIM + m]);
    out[m] = mx;
}

extern "C" void kernel_launch(void* const* d_in, const int* in_sizes, int n_in,
                              void* d_out, int out_size, void* d_ws, size_t ws_size,
                              hipStream_t stream) {
    const float* x = (const float*)d_in[0];
    const float* W = (const float*)d_in[1];
    const float* bias = (const float*)d_in[2];
    float* out = (float*)d_out;

    unsigned short* wp = (unsigned short*)d_ws;                         // 2 MB
    float* bp = (float*)((char*)d_ws + 2 * 1024 * 1024);                // 4 KB
    float* partial = (float*)((char*)d_ws + 2 * 1024 * 1024 + 4096);    // 2 MB

    prep_kernel<<<N_POOL, 256, 0, stream>>>(W, bias, wp, bp);
    gemm_kernel<<<(M_DIM / BM) * (N_POOL / BN), 256, 0, stream>>>(x, wp, bp, partial);
    reduce_kernel<<<M_DIM / 256, 256, 0, stream>>>(partial, out);
}

// Round 2
// 110.142 us; speedup vs baseline: 1.1383x; 1.1383x over previous
//
#include <hip/hip_runtime.h>
#include <hip/hip_bf16.h>

#define M_DIM 32768
#define K_DIM 1024
#define N_POOL 1024

#define BM 128
#define BN 128
#define BK 64

typedef __attribute__((ext_vector_type(8))) short bf16x8;
typedef __attribute__((ext_vector_type(4))) float f32x4;

typedef __attribute__((address_space(3))) unsigned int lds_uint;
typedef const __attribute__((address_space(1))) unsigned int g_uint;

__device__ __forceinline__ unsigned short f2bf(float f) {
    // round-to-nearest-even f32 -> bf16 (prep kernel only; tiny)
    unsigned int u = __builtin_bit_cast(unsigned int, f);
    unsigned int lsb = (u >> 16) & 1u;
    u += 0x7fffu + lsb;
    return (unsigned short)(u >> 16);
}

__device__ __forceinline__ unsigned int f2bf2(float lo, float hi) {
    // packed RNE cvt — compiler emits v_cvt_pk_bf16_f32 (m240: don't hand-asm)
    __hip_bfloat162 h2 = __float22bfloat162_rn(make_float2(lo, hi));
    union { __hip_bfloat162 h; unsigned int u; } c;
    c.h = h2;
    return c.u;
}

// ---------------- prep: fold avgpool(k=4) into weight/bias, cast to bf16 ----
__global__ __launch_bounds__(256) void prep_kernel(
        const float* __restrict__ W, const float* __restrict__ b,
        unsigned short* __restrict__ wp, float* __restrict__ bp) {
    int n = blockIdx.x;          // 0..1023 pooled output channel
    int t = threadIdx.x;         // 0..255, 4 k's each
    const float4* r0 = (const float4*)(W + (size_t)(4 * n + 0) * K_DIM);
    const float4* r1 = (const float4*)(W + (size_t)(4 * n + 1) * K_DIM);
    const float4* r2 = (const float4*)(W + (size_t)(4 * n + 2) * K_DIM);
    const float4* r3 = (const float4*)(W + (size_t)(4 * n + 3) * K_DIM);
    float4 a0 = r0[t], a1 = r1[t], a2 = r2[t], a3 = r3[t];
    float sx = (a0.x + a1.x + a2.x + a3.x) * 0.25f;
    float sy = (a0.y + a1.y + a2.y + a3.y) * 0.25f;
    float sz = (a0.z + a1.z + a2.z + a3.z) * 0.25f;
    float sw = (a0.w + a1.w + a2.w + a3.w) * 0.25f;
    ushort4 h;
    h.x = f2bf(sx); h.y = f2bf(sy); h.z = f2bf(sz); h.w = f2bf(sw);
    *(ushort4*)&wp[(size_t)n * K_DIM + t * 4] = h;
    if (t == 0)
        bp[n] = 0.25f * (b[4 * n] + b[4 * n + 1] + b[4 * n + 2] + b[4 * n + 3]);
}

// ---------------- GEMM + fused bias/gelu/rowmax partial ---------------------
// LDS layout (both As and Bs): row-major [r][BK] bf16, 128 B/row, with the
// 16 B chunk column XOR-swizzled: chunk c16 stored at (c16 ^ (r & 7)).
// As: swizzle applied on ds_write. Bs: global_load_lds writes linearly, so
// the *source* address is pre-permuted per lane (rule #21 / m173).
__global__ __launch_bounds__(256, 2) void gemm_kernel(
        const float* __restrict__ x, const unsigned short* __restrict__ wp,
        const float* __restrict__ bp, float* __restrict__ partial) {
    __shared__ unsigned short As[BM * BK];   // 16 KB
    __shared__ unsigned short Bs[BN * BK];   // 16 KB

    // XCD-chunked swizzle: each XCD owns 32 consecutive m-tiles x all 8 n-tiles
    int bid = blockIdx.x;
    int wg = (bid & 7) * 256 + (bid >> 3);
    int nblk = wg & 7;
    int mblk = wg >> 3;
    int m0 = mblk * BM;
    int n0 = nblk * BN;

    int tid = threadIdx.x;
    int lane = tid & 63;
    int wid = tid >> 6;
    int wr = wid >> 1, wc = wid & 1;   // 2x2 wave grid, each wave 64x64

    f32x4 acc[4][4];
#pragma unroll
    for (int i = 0; i < 4; ++i)
#pragma unroll
        for (int j = 0; j < 4; ++j)
            acc[i][j] = (f32x4)(0.0f);

    const float4* xg = (const float4*)x;

    for (int kt = 0; kt < K_DIM / BK; ++kt) {
        __syncthreads();   // previous tile's LDS reads done
        // ---- B stage: 16 x global_load_lds dwordx4, source pre-swizzled ----
#pragma unroll
        for (int i = 0; i < 4; ++i) {
            int ii = wid * 4 + i;
            int rsub = lane >> 3;                    // row within 8-row group
            int g = (lane & 7) ^ rsub;               // swizzled k-chunk
            int n = n0 + ii * 8 + rsub;
            int kc = kt * BK + g * 8;
            __builtin_amdgcn_global_load_lds(
                (g_uint*)(wp + (size_t)n * K_DIM + kc),
                (lds_uint*)&Bs[ii * 512], 16, 0, 0);
        }
        // ---- A stage: f32 global -> reg -> packed cvt -> swizzled ds_write ----
        float4 av[8];
#pragma unroll
        for (int j = 0; j < 4; ++j) {
            int f16 = j * 256 + tid;                 // 16B-chunk index in tile
            int r = f16 >> 3, c16 = f16 & 7;
            size_t base = (size_t)(m0 + r) * 256 + kt * 16 + c16 * 2;
            av[2 * j]     = xg[base];
            av[2 * j + 1] = xg[base + 1];
        }
#pragma unroll
        for (int j = 0; j < 4; ++j) {
            int f16 = j * 256 + tid;
            int r = f16 >> 3, c16 = f16 & 7;
            union { bf16x8 v; unsigned int u[4]; } pk;
            pk.u[0] = f2bf2(av[2 * j].x,     av[2 * j].y);
            pk.u[1] = f2bf2(av[2 * j].z,     av[2 * j].w);
            pk.u[2] = f2bf2(av[2 * j + 1].x, av[2 * j + 1].y);
            pk.u[3] = f2bf2(av[2 * j + 1].z, av[2 * j + 1].w);
            *(bf16x8*)&As[r * 64 + ((c16 ^ (r & 7)) << 3)] = pk.v;
        }
        __syncthreads();   // drains vmcnt (global_load_lds) + lgkmcnt

        // ---- compute: 2 x (8 swizzled ds_read_b128 + 16 MFMA) ----
#pragma unroll
        for (int kk = 0; kk < BK; kk += 32) {
            int c16r = (kk >> 3) + (lane >> 4);      // 16B-chunk column
            bf16x8 af[4], bff[4];
#pragma unroll
            for (int mi = 0; mi < 4; ++mi) {
                int r = wr * 64 + mi * 16 + (lane & 15);
                af[mi] = *(const bf16x8*)&As[r * 64 + ((c16r ^ (r & 7)) << 3)];
            }
#pragma unroll
            for (int ni = 0; ni < 4; ++ni) {
                int r = wc * 64 + ni * 16 + (lane & 15);
                bff[ni] = *(const bf16x8*)&Bs[r * 64 + ((c16r ^ (r & 7)) << 3)];
            }
#pragma unroll
            for (int mi = 0; mi < 4; ++mi)
#pragma unroll
                for (int ni = 0; ni < 4; ++ni)
                    acc[mi][ni] = __builtin_amdgcn_mfma_f32_16x16x32_bf16(
                        af[mi], bff[ni], acc[mi][ni], 0, 0, 0);
        }
    }

    // ---- epilogue: bias + tanh-gelu*2 + row-max over this 64-col slice ----
    float bv[4];
#pragma unroll
    for (int ni = 0; ni < 4; ++ni)
        bv[ni] = bp[n0 + wc * 64 + ni * 16 + (lane & 15)];

    const float GC = 0.7978845608028654f;
#pragma unroll
    for (int mi = 0; mi < 4; ++mi) {
#pragma unroll
        for (int j = 0; j < 4; ++j) {
            float mx = -3.4e38f;
#pragma unroll
            for (int ni = 0; ni < 4; ++ni) {
                float y = acc[mi][ni][j] + bv[ni];
                float z = GC * (y + 0.044715f * y * y * y);
                float e = __expf(2.0f * z);
                float th = 1.0f - 2.0f / (e + 1.0f);   // tanh(z)
                float g = y * (1.0f + th);             // 0.5*(1+tanh)*y*SCALE(2)
                mx = fmaxf(mx, g);
            }
#pragma unroll
            for (int s = 1; s < 16; s <<= 1)
                mx = fmaxf(mx, __shfl_xor(mx, s, 64));
            if ((lane & 15) == 0) {
                int grow = m0 + wr * 64 + mi * 16 + (lane >> 4) * 4 + j;
                partial[(size_t)(nblk * 2 + wc) * M_DIM + grow] = mx;
            }
        }
    }
}

// ---------------- final reduce: max over 16 column-chunks -------------------
__global__ __launch_bounds__(256) void reduce_kernel(
        const float* __restrict__ partial, float* __restrict__ out) {
    int m = blockIdx.x * 256 + threadIdx.x;
    float mx = -3.4e38f;
#pragma unroll
    for (int c = 0; c < 16; ++c)
        mx = fmaxf(mx, partial[(size_t)c * M_DIM + m]);
    out[m] = mx;
}

extern "C" void kernel_launch(void* const* d_in, const int* in_sizes, int n_in,
                              void* d_out, int out_size, void* d_ws, size_t ws_size,
                              hipStream_t stream) {
    const float* x = (const float*)d_in[0];
    const float* W = (const float*)d_in[1];
    const float* bias = (const float*)d_in[2];
    float* out = (float*)d_out;

    unsigned short* wp = (unsigned short*)d_ws;                         // 2 MB
    float* bp = (float*)((char*)d_ws + 2 * 1024 * 1024);                // 4 KB
    float* partial = (float*)((char*)d_ws + 2 * 1024 * 1024 + 4096);    // 2 MB

    prep_kernel<<<N_POOL, 256, 0, stream>>>(W, bias, wp, bp);
    gemm_kernel<<<(M_DIM / BM) * (N_POOL / BN), 256, 0, stream>>>(x, wp, bp, partial);
    reduce_kernel<<<M_DIM / 256, 256, 0, stream>>>(partial, out);
}